// Round 8
// baseline (247.338 us; speedup 1.0000x reference)
//
#include <hip/hip_runtime.h>
#include <hip/hip_bf16.h>
#include <cstdint>

#define B_ 4
#define H_ 80
#define W_ 80
#define CH_ 256
#define NC_ 22
#define DIM_ 256
#define NPIX (B_*H_*W_)

typedef unsigned short ushort;
typedef __attribute__((ext_vector_type(8))) short short8;     // 8 bf16 = 4 VGPR
typedef __attribute__((ext_vector_type(4))) float floatx4;    // MFMA C/D frag

__device__ __attribute__((aligned(256))) static const unsigned char zglob[256] = {};

static __device__ inline ushort f2bf(float v) {
    __hip_bfloat16 h = __float2bfloat16(v);   // RNE
    ushort r;
    __builtin_memcpy(&r, &h, 2);
    return r;
}
static __device__ inline unsigned pk2(float a, float b) {
    return (unsigned)f2bf(a) | ((unsigned)f2bf(b) << 16);
}
static __device__ inline void gll16(const void* g, void* l) {
    __builtin_amdgcn_global_load_lds((const __attribute__((address_space(1))) void*)g,
                                     (__attribute__((address_space(3))) void*)l, 16, 0, 0);
}

// ---------------------------------------------------------------------------
// prep: ONE launch fusing three independent jobs (r6/r7-proven, byte-identical)
// ---------------------------------------------------------------------------
__global__ __launch_bounds__(256) void prep(const float* __restrict__ seg,
                                            const float* __restrict__ cw,
                                            const float* __restrict__ x,
                                            float* __restrict__ ssel,
                                            ushort* __restrict__ wbT,
                                            ushort* __restrict__ xb)
{
    __shared__ ushort ls[32][260];
    if (blockIdx.x < 900) {
        const int t = blockIdx.x * 256 + threadIdx.x;     // = k*NPIX + m
        const int k = t / NPIX;
        const int m = t - k * NPIX;
        const int w = m % W_;
        const int h = (m / W_) % H_;
        const int b = m / (W_ * H_);

        const float2* c2 = (const float2*)(seg + (size_t)m * NC_);
        float cv[NC_];
        #pragma unroll
        for (int c = 0; c < NC_ / 2; ++c) { float2 v = c2[c]; cv[2*c] = v.x; cv[2*c+1] = v.y; }
        float mx = -1e30f;
        #pragma unroll
        for (int c = 0; c < NC_; ++c) mx = fmaxf(mx, cv[c]);

        const int i = k / 3, j = k % 3;
        const int hh = h + i - 1, ww = w + j - 1;
        float s = 0.f;
        if (hh >= 0 && hh < H_ && ww >= 0 && ww < W_) {
            const float2* n2 = (const float2*)(seg + ((size_t)((b * H_ + hh) * W_ + ww)) * NC_);
            #pragma unroll
            for (int c = 0; c < NC_ / 2; ++c) {
                float2 v = n2[c];
                s += (cv[2*c]   == mx) ? v.x : 0.f;
                s += (cv[2*c+1] == mx) ? v.y : 0.f;
            }
        }
        ssel[t] = s;                                      // RAW sel (norm in conv2)
    } else if (blockIdx.x < 972) {
        const int bx = blockIdx.x - 900;
        const int k  = bx / 8;
        const int c0 = (bx % 8) * 32;
        const int c    = threadIdx.x >> 3;                // 0..31
        const int seg8 = threadIdx.x & 7;                 // 0..7

        const float* src = cw + ((size_t)(c0 + c) * 9 + k) * DIM_ + seg8 * 32;
        #pragma unroll
        for (int e = 0; e < 32; e += 4) {
            float4 v = *(const float4*)(src + e);
            unsigned* dst = (unsigned*)&ls[c][seg8 * 32 + e];
            dst[0] = pk2(v.x, v.y);
            dst[1] = pk2(v.z, v.w);
        }
        __syncthreads();

        const int d = threadIdx.x;                        // 0..255
        ushort tmp[32];
        #pragma unroll
        for (int cc = 0; cc < 32; ++cc) tmp[cc] = ls[cc][d];
        uint4 o[4];
        __builtin_memcpy(o, tmp, 64);
        uint4* dst = (uint4*)(wbT + ((size_t)k * 256 + d) * 256 + c0);
        dst[0] = o[0]; dst[1] = o[1]; dst[2] = o[2]; dst[3] = o[3];
    } else if (xb != nullptr) {
        size_t idx = ((size_t)(blockIdx.x - 972) * 256 + threadIdx.x) * 8;
        const float4* s = (const float4*)(x + idx);
        float4 a = s[0], b = s[1];
        uint4 o = make_uint4(pk2(a.x, a.y), pk2(a.z, a.w), pk2(b.x, b.y), pk2(b.z, b.w));
        *(uint4*)(xb + idx) = o;
    }
}

// ---------------------------------------------------------------------------
// conv2: ROW-STAGED taps-outer implicit GEMM. 6 groups g = (i, cc-half);
// LDS buf[g&1] = 84 px x 128 ch bf16 (input row h+i-1, pixel p = col+1,
// chunk swizzle c_stored = c ^ (p&7), gll direct, source pre-swizzled).
// The 3 j-taps of a group read the SAME buffer at row p = m + j.
// Per group: stage(g+1) at top; 3 barrier-free intervals {P=A*B over 4kk;
// loadB(next) after last Breg use; O += sl[k][m]*P}; ONE barrier at end.
// 6 barriers/block total (vs 18), 126 wave-gll (vs 360). MFMA/O/epilogue
// code identical to r7's proven kernel.
// ---------------------------------------------------------------------------
__global__ __launch_bounds__(256, 3) void conv2(const ushort* __restrict__ xb,
                                                const float* __restrict__ ssel,
                                                const ushort* __restrict__ wbT,
                                                float* __restrict__ out)
{
    __shared__ __attribute__((aligned(1024))) ushort xs[2][84 * 128];  // 43008 B
    __shared__ float sl[9][80];                                        // 2880 B

    const int tid  = threadIdx.x;
    const int lane = tid & 63;
    const int wv   = tid >> 6;               // d-offset wv*32
    const int ln   = lane & 15;
    const int quad = lane >> 4;
    const int rt   = blockIdx.x;             // b*H + h
    const int b    = rt / H_;
    const int h    = rt % H_;
    const int d0   = blockIdx.y * 128;

    floatx4 O[5][2];
    #pragma unroll
    for (int i = 0; i < 5; ++i)
        #pragma unroll
        for (int jn = 0; jn < 2; ++jn)
            O[i][jn] = (floatx4){0.f, 0.f, 0.f, 0.f};

    short8 Breg[8];                  // [kk][jn] for current tap (32 VGPR)
    auto loadB = [&](int k, int cc) {
        #pragma unroll
        for (int kk = 0; kk < 4; ++kk)
            #pragma unroll
            for (int jn = 0; jn < 2; ++jn)
                Breg[kk * 2 + jn] = *(const short8*)(wbT
                    + ((size_t)k * 256 + d0 + wv * 32 + jn * 16 + ln) * 256
                    + cc + kk * 32 + quad * 8);
    };

    // stage group g's (i, cc) row-half into xs[g&1]. 21 wave-chunks of 64x16B.
    // slot s: p = s>>4 (LDS pixel, col = p-1), cph = s&15 stores clog = cph^(p&7).
    auto stage = [&](int g) {
        const int gi = g >> 1;
        const int cc = (g & 1) * 128;
        const int rr = h + gi - 1;
        const bool rowok = (rr >= 0) && (rr < H_);
        const ushort* xrow = xb + ((size_t)((b * H_ + (rowok ? rr : 0)) * W_)) * CH_ + cc;
        char* dbase = (char*)&xs[g & 1][0];
        #pragma unroll
        for (int r = 0; r < 5; ++r) {
            const int e    = r * 4 + wv;
            const int s    = e * 64 + lane;
            const int p    = s >> 4;
            const int cph  = s & 15;
            const int clog = cph ^ (p & 7);
            const bool v   = rowok && (p >= 1) && (p <= 80);
            const void* src = v ? (const void*)(xrow + (size_t)(p - 1) * CH_ + clog * 8)
                                : (const void*)zglob;
            gll16(src, dbase + (size_t)e * 1024);
        }
        if (wv == 0) {                        // wave-uniform tail chunk e=20
            const int s    = 20 * 64 + lane;
            const int p    = s >> 4;          // 80..83
            const int cph  = s & 15;
            const int clog = cph ^ (p & 7);
            const bool v   = rowok && (p <= 80);
            const void* src = v ? (const void*)(xrow + (size_t)(p - 1) * CH_ + clog * 8)
                                : (const void*)zglob;
            gll16(src, dbase + (size_t)20 * 1024);
        }
    };

    // ================= prologue =================
    stage(0);
    loadB(0, 0);
    if (tid < 80) {                           // fold norm into raw sel
        float rv[9]; int cnt = 0;
        #pragma unroll
        for (int k = 0; k < 9; ++k) {
            rv[k] = ssel[k * NPIX + rt * W_ + tid];
            cnt += (rv[k] != 0.f) ? 1 : 0;
        }
        const float norm = (cnt > 0) ? 9.f / (float)cnt : 0.f;
        #pragma unroll
        for (int k = 0; k < 9; ++k) sl[k][tid] = rv[k] * norm;
    }
    __syncthreads();                          // buf0 + Breg + sl ready

    // ================= main loop: 6 groups, one barrier each ================
    #pragma unroll 2
    for (int g = 0; g < 6; ++g) {
        const int gi = g >> 1;
        const int cc = (g & 1) * 128;
        const char* bp = (const char*)&xs[g & 1][0];

        if (g < 5) stage(g + 1);             // glls drain at end-of-group barrier

        #pragma unroll
        for (int j = 0; j < 3; ++j) {
            const int k = 3 * gi + j;

            floatx4 P[5][2];
            #pragma unroll
            for (int im = 0; im < 5; ++im)
                #pragma unroll
                for (int jn = 0; jn < 2; ++jn)
                    P[im][jn] = (floatx4){0.f, 0.f, 0.f, 0.f};

            #pragma unroll
            for (int kk = 0; kk < 4; ++kk) {
                short8 a[5];
                #pragma unroll
                for (int im = 0; im < 5; ++im) {
                    const int p = im * 16 + ln + j;          // LDS pixel row
                    a[im] = *(const short8*)(bp
                        + (size_t)p * 256
                        + ((((kk << 2) | quad) ^ (p & 7)) << 4));
                }
                #pragma unroll
                for (int im = 0; im < 5; ++im)
                    #pragma unroll
                    for (int jn = 0; jn < 2; ++jn)
                        P[im][jn] = __builtin_amdgcn_mfma_f32_16x16x32_bf16(
                            a[im], Breg[kk * 2 + jn], P[im][jn], 0, 0, 0);
            }

            // next tap's B, after last Breg use; consumed >= 1 interval later
            if (j < 2)      loadB(k + 1, cc);
            else if (g < 5) loadB(3 * ((g + 1) >> 1), ((g + 1) & 1) * 128);

            // O += sl[k][m] * P  (row m = im*16 + quad*4 + r)
            #pragma unroll
            for (int im = 0; im < 5; ++im) {
                const float4 sv = *(const float4*)&sl[k][im * 16 + quad * 4];
                #pragma unroll
                for (int jn = 0; jn < 2; ++jn) {
                    O[im][jn][0] += sv.x * P[im][jn][0];
                    O[im][jn][1] += sv.y * P[im][jn][1];
                    O[im][jn][2] += sv.z * P[im][jn][2];
                    O[im][jn][3] += sv.w * P[im][jn][3];
                }
            }
        }
        __syncthreads();                      // buf[g^1] writes done; swap
    }

    // epilogue: C/D layout col(d)=lane&15, row(m)=quad*4+reg
    #pragma unroll
    for (int im = 0; im < 5; ++im) {
        #pragma unroll
        for (int jn = 0; jn < 2; ++jn) {
            const int dd = d0 + wv * 32 + jn * 16 + ln;
            #pragma unroll
            for (int r = 0; r < 4; ++r) {
                const int m = im * 16 + quad * 4 + r;
                out[((size_t)(rt * W_ + m)) * DIM_ + dd] = O[im][jn][r];
            }
        }
    }
}

// ---------------------------------------------------------------------------
// conv2_fb: r6-proven fp32 reg-staging fallback (workspace too small for xb).
// ---------------------------------------------------------------------------
__global__ __launch_bounds__(256, 3) void conv2_fb(const float* __restrict__ x,
                                                   const float* __restrict__ ssel,
                                                   const ushort* __restrict__ wbT,
                                                   float* __restrict__ out)
{
    __shared__ ushort xsA[2][80 * 136];
    __shared__ float  sl[9][80];

    const int tid  = threadIdx.x;
    const int lane = tid & 63;
    const int wv   = tid >> 6;
    const int ln   = lane & 15;
    const int quad = lane >> 4;
    const int rt   = blockIdx.x;
    const int b    = rt / H_;
    const int h    = rt % H_;
    const int d0   = blockIdx.y * 128;

    int qm[5], qc[5];
    #pragma unroll
    for (int r = 0; r < 5; ++r) { int q = tid + 256 * r; qm[r] = q >> 4; qc[r] = q & 15; }

    floatx4 O[5][2];
    #pragma unroll
    for (int i = 0; i < 5; ++i)
        #pragma unroll
        for (int jn = 0; jn < 2; ++jn)
            O[i][jn] = (floatx4){0.f, 0.f, 0.f, 0.f};

    float4 fa[5], fb[5];
    bool   ok[5];

    auto stage_load = [&](int nit) {
        const int i = nit / 6, rem = nit % 6, cc = (rem / 3) * 128, jj = rem % 3;
        const int rr = h + i - 1;
        const bool rowok = (rr >= 0) && (rr < H_);
        const int rsafe = rowok ? rr : h;
        #pragma unroll
        for (int r = 0; r < 5; ++r) {
            const int col = qm[r] + jj - 1;
            const bool v = rowok && (col >= 0) && (col < W_);
            ok[r] = v;
            const float* f = x + ((size_t)(b * H_ + rsafe) * W_ + (v ? col : 0)) * CH_ + cc + qc[r] * 8;
            fa[r] = *(const float4*)f;
            fb[r] = *(const float4*)(f + 4);
        }
    };
    auto stage_write = [&](int nit) {
        ushort* bp = xsA[nit & 1];
        #pragma unroll
        for (int r = 0; r < 5; ++r) {
            uint4 v = ok[r] ? make_uint4(pk2(fa[r].x, fa[r].y), pk2(fa[r].z, fa[r].w),
                                         pk2(fb[r].x, fb[r].y), pk2(fb[r].z, fb[r].w))
                            : make_uint4(0u, 0u, 0u, 0u);
            *(uint4*)&xsA[nit & 1][qm[r] * 136 + qc[r] * 8] = v;
            (void)bp;
        }
    };

    short8 Breg[8];
    auto loadB = [&](int nit) {
        const int i = nit / 6, rem = nit % 6, cc = (rem / 3) * 128, jj = rem % 3;
        const int k = 3 * i + jj;
        #pragma unroll
        for (int kk = 0; kk < 4; ++kk)
            #pragma unroll
            for (int jn = 0; jn < 2; ++jn)
                Breg[kk * 2 + jn] = *(const short8*)(wbT
                    + ((size_t)k * 256 + d0 + wv * 32 + jn * 16 + ln) * 256
                    + cc + kk * 32 + quad * 8);
    };

    stage_load(0);
    if (tid < 80) {
        float rv[9]; int cnt = 0;
        #pragma unroll
        for (int k = 0; k < 9; ++k) { rv[k] = ssel[k * NPIX + rt * W_ + tid]; cnt += (rv[k] != 0.f) ? 1 : 0; }
        const float norm = (cnt > 0) ? 9.f / (float)cnt : 0.f;
        #pragma unroll
        for (int k = 0; k < 9; ++k) sl[k][tid] = rv[k] * norm;
    }
    stage_write(0);
    loadB(0);
    __syncthreads();

    #pragma unroll 2
    for (int it = 0; it < 18; ++it) {
        const int i = it / 6, rem = it % 6, jj = rem % 3;
        const int k = 3 * i + jj;
        const ushort* bp = xsA[it & 1];

        if (it < 17) stage_load(it + 1);

        floatx4 P[5][2];
        #pragma unroll
        for (int im = 0; im < 5; ++im)
            #pragma unroll
            for (int jn = 0; jn < 2; ++jn)
                P[im][jn] = (floatx4){0.f, 0.f, 0.f, 0.f};

        #pragma unroll
        for (int kk = 0; kk < 4; ++kk) {
            short8 a[5];
            #pragma unroll
            for (int im = 0; im < 5; ++im)
                a[im] = *(const short8*)&bp[(im * 16 + ln) * 136 + kk * 32 + quad * 8];
            #pragma unroll
            for (int im = 0; im < 5; ++im)
                #pragma unroll
                for (int jn = 0; jn < 2; ++jn)
                    P[im][jn] = __builtin_amdgcn_mfma_f32_16x16x32_bf16(
                        a[im], Breg[kk * 2 + jn], P[im][jn], 0, 0, 0);
        }

        if (it < 17) stage_write(it + 1);
        if (it < 17) loadB(it + 1);

        #pragma unroll
        for (int im = 0; im < 5; ++im) {
            const float4 sv = *(const float4*)&sl[k][im * 16 + quad * 4];
            #pragma unroll
            for (int jn = 0; jn < 2; ++jn) {
                O[im][jn][0] += sv.x * P[im][jn][0];
                O[im][jn][1] += sv.y * P[im][jn][1];
                O[im][jn][2] += sv.z * P[im][jn][2];
                O[im][jn][3] += sv.w * P[im][jn][3];
            }
        }
        __syncthreads();
    }

    #pragma unroll
    for (int im = 0; im < 5; ++im)
        #pragma unroll
        for (int jn = 0; jn < 2; ++jn) {
            const int dd = d0 + wv * 32 + jn * 16 + ln;
            #pragma unroll
            for (int r = 0; r < 4; ++r) {
                const int m = im * 16 + quad * 4 + r;
                out[((size_t)(rt * W_ + m)) * DIM_ + dd] = O[im][jn][r];
            }
        }
}

extern "C" void kernel_launch(void* const* d_in, const int* in_sizes, int n_in,
                              void* d_out, int out_size, void* d_ws, size_t ws_size,
                              hipStream_t stream)
{
    const float* x   = (const float*)d_in[0];   // (4,80,80,256) f32
    const float* seg = (const float*)d_in[1];   // (4,80,80,22)  f32
    const float* cw  = (const float*)d_in[2];   // (256,3,3,256) f32
    float* out = (float*)d_out;

    float*  ssel = (float*)d_ws;                                   // 921600 B (raw)
    ushort* wbT  = (ushort*)((char*)d_ws + 921600);                // 1179648 B
    ushort* xb   = (ushort*)((char*)d_ws + 921600 + 1179648);      // 13107200 B
    const size_t need = 921600u + 1179648u + 13107200u;

    if (ws_size >= need) {
        prep<<<dim3(972 + 3200), dim3(256), 0, stream>>>(seg, cw, x, ssel, wbT, xb);
        conv2<<<dim3(B_ * H_, 2), dim3(256), 0, stream>>>(xb, ssel, wbT, out);
    } else {
        prep<<<dim3(972), dim3(256), 0, stream>>>(seg, cw, x, ssel, wbT, nullptr);
        conv2_fb<<<dim3(B_ * H_, 2), dim3(256), 0, stream>>>(x, ssel, wbT, out);
    }
}

// Round 9
// 178.465 us; speedup vs baseline: 1.3859x; 1.3859x over previous
//
#include <hip/hip_runtime.h>
#include <hip/hip_bf16.h>
#include <cstdint>

#define B_ 4
#define H_ 80
#define W_ 80
#define CH_ 256
#define NC_ 22
#define DIM_ 256
#define NPIX (B_*H_*W_)

typedef unsigned short ushort;
typedef __attribute__((ext_vector_type(8))) short short8;     // 8 bf16 = 4 VGPR
typedef __attribute__((ext_vector_type(4))) float floatx4;    // MFMA C/D frag

__device__ __attribute__((aligned(256))) static const unsigned char zglob[256] = {};

static __device__ inline ushort f2bf(float v) {
    __hip_bfloat16 h = __float2bfloat16(v);   // RNE
    ushort r;
    __builtin_memcpy(&r, &h, 2);
    return r;
}
static __device__ inline unsigned pk2(float a, float b) {
    return (unsigned)f2bf(a) | ((unsigned)f2bf(b) << 16);
}
static __device__ inline void gll16(const void* g, void* l) {
    __builtin_amdgcn_global_load_lds((const __attribute__((address_space(1))) void*)g,
                                     (__attribute__((address_space(3))) void*)l, 16, 0, 0);
}

// ---------------------------------------------------------------------------
// prep: ONE launch fusing three independent jobs (r6/r7-proven, byte-identical)
// ---------------------------------------------------------------------------
__global__ __launch_bounds__(256) void prep(const float* __restrict__ seg,
                                            const float* __restrict__ cw,
                                            const float* __restrict__ x,
                                            float* __restrict__ ssel,
                                            ushort* __restrict__ wbT,
                                            ushort* __restrict__ xb)
{
    __shared__ ushort ls[32][260];
    if (blockIdx.x < 900) {
        const int t = blockIdx.x * 256 + threadIdx.x;     // = k*NPIX + m
        const int k = t / NPIX;
        const int m = t - k * NPIX;
        const int w = m % W_;
        const int h = (m / W_) % H_;
        const int b = m / (W_ * H_);

        const float2* c2 = (const float2*)(seg + (size_t)m * NC_);
        float cv[NC_];
        #pragma unroll
        for (int c = 0; c < NC_ / 2; ++c) { float2 v = c2[c]; cv[2*c] = v.x; cv[2*c+1] = v.y; }
        float mx = -1e30f;
        #pragma unroll
        for (int c = 0; c < NC_; ++c) mx = fmaxf(mx, cv[c]);

        const int i = k / 3, j = k % 3;
        const int hh = h + i - 1, ww = w + j - 1;
        float s = 0.f;
        if (hh >= 0 && hh < H_ && ww >= 0 && ww < W_) {
            const float2* n2 = (const float2*)(seg + ((size_t)((b * H_ + hh) * W_ + ww)) * NC_);
            #pragma unroll
            for (int c = 0; c < NC_ / 2; ++c) {
                float2 v = n2[c];
                s += (cv[2*c]   == mx) ? v.x : 0.f;
                s += (cv[2*c+1] == mx) ? v.y : 0.f;
            }
        }
        ssel[t] = s;                                      // RAW sel (norm in conv2)
    } else if (blockIdx.x < 972) {
        const int bx = blockIdx.x - 900;
        const int k  = bx / 8;
        const int c0 = (bx % 8) * 32;
        const int c    = threadIdx.x >> 3;                // 0..31
        const int seg8 = threadIdx.x & 7;                 // 0..7

        const float* src = cw + ((size_t)(c0 + c) * 9 + k) * DIM_ + seg8 * 32;
        #pragma unroll
        for (int e = 0; e < 32; e += 4) {
            float4 v = *(const float4*)(src + e);
            unsigned* dst = (unsigned*)&ls[c][seg8 * 32 + e];
            dst[0] = pk2(v.x, v.y);
            dst[1] = pk2(v.z, v.w);
        }
        __syncthreads();

        const int d = threadIdx.x;                        // 0..255
        ushort tmp[32];
        #pragma unroll
        for (int cc = 0; cc < 32; ++cc) tmp[cc] = ls[cc][d];
        uint4 o[4];
        __builtin_memcpy(o, tmp, 64);
        uint4* dst = (uint4*)(wbT + ((size_t)k * 256 + d) * 256 + c0);
        dst[0] = o[0]; dst[1] = o[1]; dst[2] = o[2]; dst[3] = o[3];
    } else if (xb != nullptr) {
        size_t idx = ((size_t)(blockIdx.x - 972) * 256 + threadIdx.x) * 8;
        const float4* s = (const float4*)(x + idx);
        float4 a = s[0], b = s[1];
        uint4 o = make_uint4(pk2(a.x, a.y), pk2(a.z, a.w), pk2(b.x, b.y), pk2(b.z, b.w));
        *(uint4*)(xb + idx) = o;
    }
}

// ---------------------------------------------------------------------------
// conv2: r7's PROVEN kernel (73.5 us) with the M dimension split 2x for TLP.
// Block = 40 output pixels (m0 = (bx&1)*40) x 128 d. LDS tile 48 px x 128 ch
// (rows 40..47 phantom, outputs not stored), double-buffered = 24.6 KB ->
// 4+ blocks/CU co-resident (vs 2.5): cross-block overlap hides the
// per-interval barrier drains that lockstep a single block's 4 waves.
// Staging/swizzle/Breg/O-update byte-equivalent to r7; im range 5 -> 3.
// ---------------------------------------------------------------------------
__global__ __launch_bounds__(256, 4) void conv2(const ushort* __restrict__ xb,
                                                const float* __restrict__ ssel,
                                                const ushort* __restrict__ wbT,
                                                float* __restrict__ out)
{
    __shared__ __attribute__((aligned(1024))) ushort xs[2][48 * 128];  // 24576 B
    __shared__ float sl[9][48];                                        // 1728 B

    const int tid  = threadIdx.x;
    const int lane = tid & 63;
    const int wv   = tid >> 6;               // d-offset wv*32
    const int ln   = lane & 15;
    const int quad = lane >> 4;
    const int bx   = blockIdx.x;
    const int rt   = bx >> 1;                // b*H + h
    const int m0   = (bx & 1) * 40;          // pixel-half offset
    const int b    = rt / H_;
    const int h    = rt % H_;
    const int d0   = blockIdx.y * 128;

    floatx4 O[3][2];
    #pragma unroll
    for (int i = 0; i < 3; ++i)
        #pragma unroll
        for (int jn = 0; jn < 2; ++jn)
            O[i][jn] = (floatx4){0.f, 0.f, 0.f, 0.f};

    short8 Breg[8];                  // [kk][jn] for current interval (32 VGPR)
    auto loadB = [&](int nit) {
        const int i   = nit / 6;
        const int rem = nit % 6;
        const int cc  = (rem / 3) * 128;
        const int jj  = rem % 3;
        const int k   = 3 * i + jj;
        #pragma unroll
        for (int kk = 0; kk < 4; ++kk)
            #pragma unroll
            for (int jn = 0; jn < 2; ++jn)
                Breg[kk * 2 + jn] = *(const short8*)(wbT
                    + ((size_t)k * 256 + d0 + wv * 32 + jn * 16 + ln) * 256
                    + cc + kk * 32 + quad * 8);
    };

    // stage interval nit into xs[nit&1] via global_load_lds.
    // 48 rows x 16 chunks = 768 slots = 12 full wave-chunks (3 per wave).
    // slot s: p = s>>4 (LDS row = output pixel m0+p), cph = s&15 stores
    // global chunk clog = cph ^ (p&7); source col = m0 + p + jj - 1.
    auto stage = [&](int nit) {
        const int i   = nit / 6;
        const int rem = nit % 6;
        const int cc  = (rem / 3) * 128;
        const int jj  = rem % 3;
        const int rr  = h + i - 1;
        const bool rowok = (rr >= 0) && (rr < H_);
        const ushort* xrow = xb + ((size_t)((b * H_ + (rowok ? rr : 0)) * W_)) * CH_ + cc;
        char* dbase = (char*)&xs[nit & 1][0];
        #pragma unroll
        for (int r = 0; r < 3; ++r) {
            const int e    = r * 4 + wv;      // 0..11
            const int s    = e * 64 + lane;
            const int p    = s >> 4;          // 0..47
            const int cph  = s & 15;
            const int clog = cph ^ (p & 7);
            const int col  = m0 + p + jj - 1;
            const bool v   = rowok && (col >= 0) && (col < W_);
            const void* src = v ? (const void*)(xrow + (size_t)col * CH_ + clog * 8)
                                : (const void*)zglob;
            gll16(src, dbase + (size_t)e * 1024);
        }
    };

    // ================= prologue =================
    stage(0);
    loadB(0);
    if (tid < 48) {                           // fold norm into raw sel (40 valid)
        if (tid < 40) {
            float rv[9]; int cnt = 0;
            #pragma unroll
            for (int k = 0; k < 9; ++k) {
                rv[k] = ssel[k * NPIX + rt * W_ + m0 + tid];
                cnt += (rv[k] != 0.f) ? 1 : 0;
            }
            const float norm = (cnt > 0) ? 9.f / (float)cnt : 0.f;
            #pragma unroll
            for (int k = 0; k < 9; ++k) sl[k][tid] = rv[k] * norm;
        } else {
            #pragma unroll
            for (int k = 0; k < 9; ++k) sl[k][tid] = 0.f;
        }
    }
    __syncthreads();                          // buf0 + Breg + sl ready

    // ================= main loop (r7 schedule verbatim) =================
    #pragma unroll 2
    for (int it = 0; it < 18; ++it) {
        const int i   = it / 6;
        const int rem = it % 6;
        const int jj  = rem % 3;
        const int k   = 3 * i + jj;
        const char* bp = (const char*)&xs[it & 1][0];

        if (it < 17) stage(it + 1);          // 12 gll, no dependents, drain at bar

        floatx4 P[3][2];
        #pragma unroll
        for (int im = 0; im < 3; ++im)
            #pragma unroll
            for (int jn = 0; jn < 2; ++jn)
                P[im][jn] = (floatx4){0.f, 0.f, 0.f, 0.f};

        #pragma unroll
        for (int kk = 0; kk < 4; ++kk) {
            short8 a[3];
            #pragma unroll
            for (int im = 0; im < 3; ++im)
                a[im] = *(const short8*)(bp
                    + (size_t)(im * 16 + ln) * 256
                    + ((((kk << 2) | quad) ^ (ln & 7)) << 4));
            #pragma unroll
            for (int im = 0; im < 3; ++im)
                #pragma unroll
                for (int jn = 0; jn < 2; ++jn)
                    P[im][jn] = __builtin_amdgcn_mfma_f32_16x16x32_bf16(
                        a[im], Breg[kk * 2 + jn], P[im][jn], 0, 0, 0);
        }

        if (it < 17) loadB(it + 1);          // after last Breg use; used after bar

        // scale-accumulate: O += s_k[m] * P  (row m = im*16 + quad*4 + r)
        #pragma unroll
        for (int im = 0; im < 3; ++im) {
            const float4 sv = *(const float4*)&sl[k][im * 16 + quad * 4];
            #pragma unroll
            for (int jn = 0; jn < 2; ++jn) {
                O[im][jn][0] += sv.x * P[im][jn][0];
                O[im][jn][1] += sv.y * P[im][jn][1];
                O[im][jn][2] += sv.z * P[im][jn][2];
                O[im][jn][3] += sv.w * P[im][jn][3];
            }
        }
        __syncthreads();
    }

    // epilogue: C/D layout col(d)=lane&15, row(m)=quad*4+reg; skip phantom rows
    #pragma unroll
    for (int im = 0; im < 3; ++im) {
        if (im < 2 || quad < 2) {
            #pragma unroll
            for (int jn = 0; jn < 2; ++jn) {
                const int dd = d0 + wv * 32 + jn * 16 + ln;
                #pragma unroll
                for (int r = 0; r < 4; ++r) {
                    const int m = m0 + im * 16 + quad * 4 + r;
                    out[((size_t)(rt * W_ + m)) * DIM_ + dd] = O[im][jn][r];
                }
            }
        }
    }
}

// ---------------------------------------------------------------------------
// conv2_fb: r6-proven fp32 reg-staging fallback (workspace too small for xb).
// ---------------------------------------------------------------------------
__global__ __launch_bounds__(256, 3) void conv2_fb(const float* __restrict__ x,
                                                   const float* __restrict__ ssel,
                                                   const ushort* __restrict__ wbT,
                                                   float* __restrict__ out)
{
    __shared__ ushort xsA[2][80 * 136];
    __shared__ float  sl[9][80];

    const int tid  = threadIdx.x;
    const int lane = tid & 63;
    const int wv   = tid >> 6;
    const int ln   = lane & 15;
    const int quad = lane >> 4;
    const int rt   = blockIdx.x;
    const int b    = rt / H_;
    const int h    = rt % H_;
    const int d0   = blockIdx.y * 128;

    int qm[5], qc[5];
    #pragma unroll
    for (int r = 0; r < 5; ++r) { int q = tid + 256 * r; qm[r] = q >> 4; qc[r] = q & 15; }

    floatx4 O[5][2];
    #pragma unroll
    for (int i = 0; i < 5; ++i)
        #pragma unroll
        for (int jn = 0; jn < 2; ++jn)
            O[i][jn] = (floatx4){0.f, 0.f, 0.f, 0.f};

    float4 fa[5], fb[5];
    bool   ok[5];

    auto stage_load = [&](int nit) {
        const int i = nit / 6, rem = nit % 6, cc = (rem / 3) * 128, jj = rem % 3;
        const int rr = h + i - 1;
        const bool rowok = (rr >= 0) && (rr < H_);
        const int rsafe = rowok ? rr : h;
        #pragma unroll
        for (int r = 0; r < 5; ++r) {
            const int col = qm[r] + jj - 1;
            const bool v = rowok && (col >= 0) && (col < W_);
            ok[r] = v;
            const float* f = x + ((size_t)(b * H_ + rsafe) * W_ + (v ? col : 0)) * CH_ + cc + qc[r] * 8;
            fa[r] = *(const float4*)f;
            fb[r] = *(const float4*)(f + 4);
        }
    };
    auto stage_write = [&](int nit) {
        #pragma unroll
        for (int r = 0; r < 5; ++r) {
            uint4 v = ok[r] ? make_uint4(pk2(fa[r].x, fa[r].y), pk2(fa[r].z, fa[r].w),
                                         pk2(fb[r].x, fb[r].y), pk2(fb[r].z, fb[r].w))
                            : make_uint4(0u, 0u, 0u, 0u);
            *(uint4*)&xsA[nit & 1][qm[r] * 136 + qc[r] * 8] = v;
        }
    };

    short8 Breg[8];
    auto loadB = [&](int nit) {
        const int i = nit / 6, rem = nit % 6, cc = (rem / 3) * 128, jj = rem % 3;
        const int k = 3 * i + jj;
        #pragma unroll
        for (int kk = 0; kk < 4; ++kk)
            #pragma unroll
            for (int jn = 0; jn < 2; ++jn)
                Breg[kk * 2 + jn] = *(const short8*)(wbT
                    + ((size_t)k * 256 + d0 + wv * 32 + jn * 16 + ln) * 256
                    + cc + kk * 32 + quad * 8);
    };

    stage_load(0);
    if (tid < 80) {
        float rv[9]; int cnt = 0;
        #pragma unroll
        for (int k = 0; k < 9; ++k) { rv[k] = ssel[k * NPIX + rt * W_ + tid]; cnt += (rv[k] != 0.f) ? 1 : 0; }
        const float norm = (cnt > 0) ? 9.f / (float)cnt : 0.f;
        #pragma unroll
        for (int k = 0; k < 9; ++k) sl[k][tid] = rv[k] * norm;
    }
    stage_write(0);
    loadB(0);
    __syncthreads();

    #pragma unroll 2
    for (int it = 0; it < 18; ++it) {
        const int i = it / 6, rem = it % 6, jj = rem % 3;
        const int k = 3 * i + jj;
        const ushort* bp = xsA[it & 1];

        if (it < 17) stage_load(it + 1);

        floatx4 P[5][2];
        #pragma unroll
        for (int im = 0; im < 5; ++im)
            #pragma unroll
            for (int jn = 0; jn < 2; ++jn)
                P[im][jn] = (floatx4){0.f, 0.f, 0.f, 0.f};

        #pragma unroll
        for (int kk = 0; kk < 4; ++kk) {
            short8 a[5];
            #pragma unroll
            for (int im = 0; im < 5; ++im)
                a[im] = *(const short8*)&bp[(im * 16 + ln) * 136 + kk * 32 + quad * 8];
            #pragma unroll
            for (int im = 0; im < 5; ++im)
                #pragma unroll
                for (int jn = 0; jn < 2; ++jn)
                    P[im][jn] = __builtin_amdgcn_mfma_f32_16x16x32_bf16(
                        a[im], Breg[kk * 2 + jn], P[im][jn], 0, 0, 0);
        }

        if (it < 17) stage_write(it + 1);
        if (it < 17) loadB(it + 1);

        #pragma unroll
        for (int im = 0; im < 5; ++im) {
            const float4 sv = *(const float4*)&sl[k][im * 16 + quad * 4];
            #pragma unroll
            for (int jn = 0; jn < 2; ++jn) {
                O[im][jn][0] += sv.x * P[im][jn][0];
                O[im][jn][1] += sv.y * P[im][jn][1];
                O[im][jn][2] += sv.z * P[im][jn][2];
                O[im][jn][3] += sv.w * P[im][jn][3];
            }
        }
        __syncthreads();
    }

    #pragma unroll
    for (int im = 0; im < 5; ++im)
        #pragma unroll
        for (int jn = 0; jn < 2; ++jn) {
            const int dd = d0 + wv * 32 + jn * 16 + ln;
            #pragma unroll
            for (int r = 0; r < 4; ++r) {
                const int m = im * 16 + quad * 4 + r;
                out[((size_t)(rt * W_ + m)) * DIM_ + dd] = O[im][jn][r];
            }
        }
}

extern "C" void kernel_launch(void* const* d_in, const int* in_sizes, int n_in,
                              void* d_out, int out_size, void* d_ws, size_t ws_size,
                              hipStream_t stream)
{
    const float* x   = (const float*)d_in[0];   // (4,80,80,256) f32
    const float* seg = (const float*)d_in[1];   // (4,80,80,22)  f32
    const float* cw  = (const float*)d_in[2];   // (256,3,3,256) f32
    float* out = (float*)d_out;

    float*  ssel = (float*)d_ws;                                   // 921600 B (raw)
    ushort* wbT  = (ushort*)((char*)d_ws + 921600);                // 1179648 B
    ushort* xb   = (ushort*)((char*)d_ws + 921600 + 1179648);      // 13107200 B
    const size_t need = 921600u + 1179648u + 13107200u;

    if (ws_size >= need) {
        prep<<<dim3(972 + 3200), dim3(256), 0, stream>>>(seg, cw, x, ssel, wbT, xb);
        conv2<<<dim3(B_ * H_ * 2, 2), dim3(256), 0, stream>>>(xb, ssel, wbT, out);
    } else {
        prep<<<dim3(972), dim3(256), 0, stream>>>(seg, cw, x, ssel, wbT, nullptr);
        conv2_fb<<<dim3(B_ * H_, 2), dim3(256), 0, stream>>>(x, ssel, wbT, out);
    }
}